// Round 1
// baseline (43.801 us; speedup 1.0000x reference)
//
#include <hip/hip_runtime.h>
#include <hip/hip_bf16.h>

// AP (Aliev-Panfilov) model RHS:
//   u = y[:D], v = y[D:2D]
//   MK = S @ u                       (dense f32 GEMV, D=8192 -> 256 MiB of S)
//   pde1 = MK + k*u*(1-u)*(u-par) - u*v
//   pde2 = -e*(k*u*(u-par-1) + v)
// out = concat(pde1, pde2), float32.
//
// Memory-bound on the S read. One wave per row, float4 loads, shuffle reduce.

#define DIM_D 8192

__global__ __launch_bounds__(256) void apmodel_gemv_kernel(
    const float* __restrict__ y,
    const float* __restrict__ S,
    const float* __restrict__ par,
    float* __restrict__ out)
{
    const int D = DIM_D;
    const int wave_in_block = threadIdx.x >> 6;     // 0..3
    const int lane = threadIdx.x & 63;
    const int row = blockIdx.x * 4 + wave_in_block; // one wave per row
    if (row >= D) return;

    const float4* __restrict__ Srow =
        reinterpret_cast<const float4*>(S + (size_t)row * D);
    const float4* __restrict__ u4 =
        reinterpret_cast<const float4*>(y);

    // D/4 = 2048 float4's per row; 64 lanes -> 32 iterations/lane.
    // Unroll 2x for a little extra MLP (2 outstanding loads/lane).
    float acc = 0.0f;
    #pragma unroll
    for (int j0 = 0; j0 < (DIM_D / 4); j0 += 128) {
        const int ja = j0 + lane;
        const int jb = j0 + 64 + lane;
        float4 sa = Srow[ja];
        float4 sb = Srow[jb];
        float4 ua = u4[ja];
        float4 ub = u4[jb];
        acc += sa.x * ua.x + sa.y * ua.y + sa.z * ua.z + sa.w * ua.w;
        acc += sb.x * ub.x + sb.y * ub.y + sb.z * ub.z + sb.w * ub.w;
    }

    // Wave-64 butterfly reduce.
    #pragma unroll
    for (int off = 32; off > 0; off >>= 1)
        acc += __shfl_down(acc, off, 64);

    if (lane == 0) {
        const float u = y[row];
        const float v = y[D + row];
        const float p = par[row];
        const float k = 8.0f;
        const float e = 0.01f;
        const float ku = k * u;
        const float pde1 = acc + ku * (1.0f - u) * (u - p) - u * v;
        const float pde2 = -e * (ku * (u - p - 1.0f) + v);
        out[row] = pde1;
        out[D + row] = pde2;
    }
}

extern "C" void kernel_launch(void* const* d_in, const int* in_sizes, int n_in,
                              void* d_out, int out_size, void* d_ws, size_t ws_size,
                              hipStream_t stream) {
    // inputs: 0=t (1), 1=y (2D), 2=S (D*D), 3=par (D)
    const float* y   = (const float*)d_in[1];
    const float* S   = (const float*)d_in[2];
    const float* par = (const float*)d_in[3];
    float* out = (float*)d_out;

    const int rows_per_block = 4;            // 256 threads = 4 waves
    const int grid = DIM_D / rows_per_block; // 2048 blocks
    apmodel_gemv_kernel<<<grid, 256, 0, stream>>>(y, S, par, out);
}